// Round 3
// baseline (974.146 us; speedup 1.0000x reference)
//
#include <hip/hip_runtime.h>

// CCN layer promotion: promotions[n,c,a,b,s] = chi[n,c,a]*chi[n,c,b]*feat[n,c,s]
// chi[n,c,a] = (neigh[n,a] == neigh[n,c]); feat[n,c,:] = tensors[neigh[n,c],:].
// neigh rows are pre-sorted, so new_parts == neigh (output 1, stored as float).
//
// Store-bandwidth problem: 984 MB of output per call. Roofline ~156 us at
// 6.3 TB/s. Round-2 post-mortem: hot-loop changes were neutral -> kernel is
// bound by wave churn / per-wave setup latency (60k short-lived waves doing
// 16 stores each), not by VALU. Round 3: persistent waves — 5000 waves, each
// owning 4 contiguous nodes (192 stores/wave), setup amortized 12x.

constexpr int NN = 20000;
constexpr int DD = 16;
constexpr int FF = 3;
constexpr int PROMO_PER_NODE = DD * DD * DD * FF;                 // 12288 floats
constexpr long long PROMO_TOTAL = (long long)NN * PROMO_PER_NODE; // 245,760,000

constexpr int TPB    = 128;   // 2 waves/block
constexpr int BLOCKS = 2500;  // 5000 waves total
constexpr int NPW    = 4;     // nodes per wave: 20000 / 5000 exactly

#define RFL(x) __builtin_amdgcn_readfirstlane(x)

__global__ __launch_bounds__(TPB) void ccn_promote_kernel(
    const float* __restrict__ tensors,
    const int*   __restrict__ neigh,
    float*       __restrict__ out)
{
    const int lane = threadIdx.x & 63;
    const int wv   = RFL(blockIdx.x * (TPB / 64) + (threadIdx.x >> 6));

    // Per-lane constants for j=0..2: t = j*64+lane indexes the 192 float4
    // of one c-slab (16 a-slots x 48 floats). a = t/12, float4 covers flat
    // elems 4k..4k+3 with k = t%12; elem e -> (b = e/3, s = e%3).
    int aa[3], b0[3], b1[3], b2[3], b3[3], s0[3], s1[3], s2[3], s3[3];
#pragma unroll
    for (int j = 0; j < 3; ++j) {
        const int t  = j * 64 + lane;
        const int a  = t / 12;
        const int k  = t - a * 12;
        const int e0 = 4 * k;
        aa[j] = a;
        b0[j] = (e0 + 0) / 3; s0[j] = (e0 + 0) % 3;
        b1[j] = (e0 + 1) / 3; s1[j] = (e0 + 1) % 3;
        b2[j] = (e0 + 2) / 3; s2[j] = (e0 + 2) % 3;
        b3[j] = (e0 + 3) / 3; s3[j] = (e0 + 3) % 3;
    }

#pragma unroll 1   // keep body ~10KB, inside 32KB I-cache
    for (int i = 0; i < NPW; ++i) {
        const int n = wv * NPW + i;
        const int* nrow = neigh + (size_t)n * DD;

        // wave-uniform child ids -> SGPRs (broadcast loads + readfirstlane)
        const int4 r0 = ((const int4*)nrow)[0];
        const int4 r1 = ((const int4*)nrow)[1];
        const int4 r2 = ((const int4*)nrow)[2];
        const int4 r3 = ((const int4*)nrow)[3];
        int mc[DD];
        mc[ 0]=RFL(r0.x); mc[ 1]=RFL(r0.y); mc[ 2]=RFL(r0.z); mc[ 3]=RFL(r0.w);
        mc[ 4]=RFL(r1.x); mc[ 5]=RFL(r1.y); mc[ 6]=RFL(r1.z); mc[ 7]=RFL(r1.w);
        mc[ 8]=RFL(r2.x); mc[ 9]=RFL(r2.y); mc[10]=RFL(r2.z); mc[11]=RFL(r2.w);
        mc[12]=RFL(r3.x); mc[13]=RFL(r3.y); mc[14]=RFL(r3.z); mc[15]=RFL(r3.w);

        // output 1: new_parts (== sorted neigh) as float
        if (lane < DD)
            out[PROMO_TOTAL + (size_t)n * DD + lane] = (float)nrow[lane];

        // per-lane neighbor ids at this lane's (a, b0..b3) slots (L1-hot row)
        int va[3], vb0[3], vb1[3], vb2[3], vb3[3];
#pragma unroll
        for (int j = 0; j < 3; ++j) {
            va [j] = nrow[aa[j]];
            vb0[j] = nrow[b0[j]];
            vb1[j] = nrow[b1[j]];
            vb2[j] = nrow[b2[j]];
            vb3[j] = nrow[b3[j]];
        }

        // features of the 16 children, wave-uniform (SGPR-addressed loads)
        float f0[DD], f1[DD], f2[DD];
#pragma unroll
        for (int c = 0; c < DD; ++c) {
            const float* src = tensors + (size_t)mc[c] * FF;
            f0[c] = src[0]; f1[c] = src[1]; f2[c] = src[2];
        }

        float4* outv = reinterpret_cast<float4*>(out + (size_t)n * PROMO_PER_NODE);
#pragma unroll
        for (int c = 0; c < DD; ++c) {
            const int   m  = mc[c];
            const float g0 = f0[c], g1 = f1[c], g2 = f2[c];
#pragma unroll
            for (int j = 0; j < 3; ++j) {
                const bool ca = (va[j] == m);
                float4 v;
                v.x = (ca && (vb0[j] == m)) ? (s0[j]==0 ? g0 : (s0[j]==1 ? g1 : g2)) : 0.0f;
                v.y = (ca && (vb1[j] == m)) ? (s1[j]==0 ? g0 : (s1[j]==1 ? g1 : g2)) : 0.0f;
                v.z = (ca && (vb2[j] == m)) ? (s2[j]==0 ? g0 : (s2[j]==1 ? g1 : g2)) : 0.0f;
                v.w = (ca && (vb3[j] == m)) ? (s3[j]==0 ? g0 : (s3[j]==1 ? g1 : g2)) : 0.0f;
                // 64 lanes x 16B = 1KB contiguous per store instruction
                outv[c * 192 + j * 64 + lane] = v;
            }
        }
    }
}

extern "C" void kernel_launch(void* const* d_in, const int* in_sizes, int n_in,
                              void* d_out, int out_size, void* d_ws, size_t ws_size,
                              hipStream_t stream) {
    const float* tensors = (const float*)d_in[0];  // [N, F] float32
    const int*   neigh   = (const int*)d_in[1];    // [N, D] int32 (sorted rows)
    float*       out     = (float*)d_out;          // promotions flat + new_parts flat

    ccn_promote_kernel<<<BLOCKS, TPB, 0, stream>>>(tensors, neigh, out);
}